// Round 4
// baseline (245.479 us; speedup 1.0000x reference)
//
#include <hip/hip_runtime.h>

// Octree cross-entropy loss.
// D=256, BS=16 -> 4096 level-0 blocks of 16^3 voxels.
// Level 0 loss = sum_blocks mean_voxels(nll) = (sum over ALL voxels nll)/4096
//   -> no per-block grouping needed for the loss itself.
// Levels 1..4 (b = 32,64,128,256): 3-class CE (pure0/pure1/mixed) * b^3,
// class from per-16^3-block popcounts aggregated upward.
//
// R3 -> R4 changes:
//  - level0: ONE WAVE per 16^3 block (4096 waves total), software-pipelined
//    loop over 8 groups of 2 x-planes (6 vector loads/iter, prefetch next
//    group while computing current). No __syncthreads, no LDS: wave-private
//    accumulation + shuffle reduce at the end. R3 showed blocks ran
//    load->barrier->exit sequentially per CU (47% occupancy, 2.6 TB/s);
//    this keeps every wave issuing loads continuously like the 6.9 TB/s
//    fill kernel.

__device__ __forceinline__ float softplus(float x) {
    // log(1 + e^x), stable
    return fmaxf(x, 0.f) + __logf(1.f + __expf(-fabsf(x)));
}

__device__ __forceinline__ float nll3(const float* __restrict__ l, int c) {
    float a = l[0], b = l[1], d = l[2];
    float m = fmaxf(fmaxf(a, b), d);
    float lse = m + __logf(__expf(a - m) + __expf(b - m) + __expf(d - m));
    return lse - l[c];
}

__device__ __forceinline__ void accum(const int4 g, const float4 a, const float4 b,
                                      float& lsum, int& ones) {
    const float dx = a.x - b.x;
    const float dy = a.y - b.y;
    const float dz = a.z - b.z;
    const float dw = a.w - b.w;
    const int t0 = g.x > 0, t1 = g.y > 0, t2 = g.z > 0, t3 = g.w > 0;
    ones += t0 + t1 + t2 + t3;
    // target=1 -> nll = softplus(l0-l1); target=0 -> softplus(-(l0-l1))
    lsum += softplus(t0 ? dx : -dx);
    lsum += softplus(t1 ? dy : -dy);
    lsum += softplus(t2 ? dz : -dz);
    lsum += softplus(t3 ? dw : -dw);
}

// 1024 blocks x 256 threads = 4096 waves; wave w owns octree block w.
__global__ __launch_bounds__(256) void level0_kernel(
    const int* __restrict__ gt,        // [256^3], values +-1, x-major (x,y,z)
    const float* __restrict__ logits,  // [4096, 2, 4096]
    float* __restrict__ partial,       // [4096] per-block SUM of nll (un-normalized)
    int* __restrict__ ones_count)      // [4096] per-block popcount of gt01
{
    const int blk  = ((blockIdx.x << 8) + threadIdx.x) >> 6;  // 0..4095
    const int lane = threadIdx.x & 63;
    const int bx = blk >> 8;
    const int by = (blk >> 4) & 15;
    const int bz = blk & 15;

    const float* lg0 = logits + (size_t)blk * 8192;
    const float* lg1 = lg0 + 4096;

    // lane-constant pieces: lane covers iy = lane>>2, iz = (lane&3)*4 .. +3
    const int iy  = lane >> 2;
    const int izb = (lane & 3) << 2;
    // gt address for x-plane 0 of this block, this lane:
    const int gbase = ((bx * 16) << 16) + (((by * 16) + iy) << 8) + bz * 16 + izb;
    // within-block logits offset for x-plane 0, this lane:
    const int lvoff = lane << 2;

    float lsum = 0.f;
    int   ones = 0;

    // pipelined loop over 8 groups of 2 x-planes (x = 2it, 2it+1)
    int4   g0c, g1c;
    float4 a0c, a1c, b0c, b1c;
    g0c = *reinterpret_cast<const int4*>(gt + gbase);
    g1c = *reinterpret_cast<const int4*>(gt + gbase + 65536);
    a0c = *reinterpret_cast<const float4*>(lg0 + lvoff);
    a1c = *reinterpret_cast<const float4*>(lg0 + lvoff + 256);
    b0c = *reinterpret_cast<const float4*>(lg1 + lvoff);
    b1c = *reinterpret_cast<const float4*>(lg1 + lvoff + 256);

#pragma unroll 1
    for (int it = 0; it < 7; ++it) {
        const int gp = gbase + (it + 1) * 131072;   // 2 x-planes = 2*65536 ints
        const int vp = lvoff + (it + 1) * 512;      // 2 planes = 512 floats
        int4   g0n = *reinterpret_cast<const int4*>(gt + gp);
        int4   g1n = *reinterpret_cast<const int4*>(gt + gp + 65536);
        float4 a0n = *reinterpret_cast<const float4*>(lg0 + vp);
        float4 a1n = *reinterpret_cast<const float4*>(lg0 + vp + 256);
        float4 b0n = *reinterpret_cast<const float4*>(lg1 + vp);
        float4 b1n = *reinterpret_cast<const float4*>(lg1 + vp + 256);
        accum(g0c, a0c, b0c, lsum, ones);
        accum(g1c, a1c, b1c, lsum, ones);
        g0c = g0n; g1c = g1n;
        a0c = a0n; a1c = a1n;
        b0c = b0n; b1c = b1n;
    }
    accum(g0c, a0c, b0c, lsum, ones);
    accum(g1c, a1c, b1c, lsum, ones);

    // wave-private reduction; no LDS, no barrier
#pragma unroll
    for (int s = 32; s > 0; s >>= 1) {
        lsum += __shfl_down(lsum, s, 64);
        ones += __shfl_down(ones, s, 64);
    }
    if (lane == 0) {
        partial[blk] = lsum;          // un-normalized block sum
        ones_count[blk] = ones;
    }
}

// Single block, 512 threads: reduce level-0 partials (scaled by 1/4096),
// hierarchical popcount aggregation, 3-class CE for levels 1..4, write out[0].
__global__ __launch_bounds__(512) void levels_kernel(
    const float* __restrict__ partial, // [4096] block sums
    const int* __restrict__ cnt0,      // [4096] ordered (bx*16+by)*16+bz
    const float* __restrict__ l1,      // [512,3]
    const float* __restrict__ l2,      // [64,3]
    const float* __restrict__ l3,      // [8,3]
    const float* __restrict__ l4,      // [1,3]
    float* __restrict__ out)
{
    __shared__ int   s1[512];
    __shared__ int   s2[64];
    __shared__ int   s3[8];
    __shared__ float red[512];
    const int tid = threadIdx.x;
    float contrib = 0.f;

    // level-0 partial losses: 8 floats per thread, scale by 1/4096 (block mean)
    {
        const float4 p0 = *reinterpret_cast<const float4*>(partial + tid * 8);
        const float4 p1 = *reinterpret_cast<const float4*>(partial + tid * 8 + 4);
        contrib += ((p0.x + p0.y + p0.z + p0.w) + (p1.x + p1.y + p1.z + p1.w))
                 * (1.0f / 4096.0f);
    }

    // level 1: 8^3 blocks, each aggregates 2^3 level-0 blocks (16^3 grid)
    {
        const int X = tid >> 6, Y = (tid >> 3) & 7, Z = tid & 7;
        int s = 0;
#pragma unroll
        for (int dx = 0; dx < 2; ++dx)
#pragma unroll
            for (int dy = 0; dy < 2; ++dy)
#pragma unroll
                for (int dz = 0; dz < 2; ++dz)
                    s += cnt0[((X * 2 + dx) * 16 + (Y * 2 + dy)) * 16 + (Z * 2 + dz)];
        s1[tid] = s;
        const int tot = 8 * 4096;
        const int c = (s == 0) ? 0 : ((s == tot) ? 1 : 2);
        contrib += nll3(l1 + tid * 3, c) * 32768.0f;      // 32^3
    }
    __syncthreads();
    // level 2: 4^3 blocks from 8^3 grid
    if (tid < 64) {
        const int X = tid >> 4, Y = (tid >> 2) & 3, Z = tid & 3;
        int s = 0;
#pragma unroll
        for (int dx = 0; dx < 2; ++dx)
#pragma unroll
            for (int dy = 0; dy < 2; ++dy)
#pragma unroll
                for (int dz = 0; dz < 2; ++dz)
                    s += s1[((X * 2 + dx) * 8 + (Y * 2 + dy)) * 8 + (Z * 2 + dz)];
        s2[tid] = s;
        const int tot = 64 * 4096;
        const int c = (s == 0) ? 0 : ((s == tot) ? 1 : 2);
        contrib += nll3(l2 + tid * 3, c) * 262144.0f;     // 64^3
    }
    __syncthreads();
    // level 3: 2^3 blocks from 4^3 grid
    if (tid < 8) {
        const int X = tid >> 2, Y = (tid >> 1) & 1, Z = tid & 1;
        int s = 0;
#pragma unroll
        for (int dx = 0; dx < 2; ++dx)
#pragma unroll
            for (int dy = 0; dy < 2; ++dy)
#pragma unroll
                for (int dz = 0; dz < 2; ++dz)
                    s += s2[((X * 2 + dx) * 4 + (Y * 2 + dy)) * 4 + (Z * 2 + dz)];
        s3[tid] = s;
        const int tot = 512 * 4096;
        const int c = (s == 0) ? 0 : ((s == tot) ? 1 : 2);
        contrib += nll3(l3 + tid * 3, c) * 2097152.0f;    // 128^3
    }
    __syncthreads();
    // level 4: 1 block = everything
    if (tid == 0) {
        int s = 0;
#pragma unroll
        for (int i = 0; i < 8; ++i) s += s3[i];
        const int tot = 4096 * 4096;
        const int c = (s == 0) ? 0 : ((s == tot) ? 1 : 2);
        contrib += nll3(l4, c) * 16777216.0f;             // 256^3
    }

    red[tid] = contrib;
    __syncthreads();
#pragma unroll
    for (int s = 256; s > 0; s >>= 1) {
        if (tid < s) red[tid] += red[tid + s];
        __syncthreads();
    }
    if (tid == 0) out[0] = red[0];
}

extern "C" void kernel_launch(void* const* d_in, const int* in_sizes, int n_in,
                              void* d_out, int out_size, void* d_ws, size_t ws_size,
                              hipStream_t stream) {
    const int*   gt    = (const int*)d_in[0];
    const float* dense = (const float*)d_in[1];
    const float* l1    = (const float*)d_in[2];
    const float* l2    = (const float*)d_in[3];
    const float* l3    = (const float*)d_in[4];
    const float* l4    = (const float*)d_in[5];
    float* out = (float*)d_out;

    float* partial = (float*)d_ws;            // 4096 floats
    int*   cnt     = (int*)(partial + 4096);  // 4096 ints

    level0_kernel<<<1024, 256, 0, stream>>>(gt, dense, partial, cnt);
    levels_kernel<<<1, 512, 0, stream>>>(partial, cnt, l1, l2, l3, l4, out);
}